// Round 9
// baseline (143.958 us; speedup 1.0000x reference)
//
#include <hip/hip_runtime.h>

// VoxelNet MI355X. Batch collapsed to 1 (identical slots; BN stats invariant).
// conv1/conv2/head all bf16 MFMA 32x32x16, fp32 accumulate, LDS-window
// implicit GEMM. R9: conv2m = 8h x 8w x 4d tile (625 blocks), 4 waves,
// wave = (co-half x d-pair) so each wave streams only HALF of packed W2
// (A-L2 traffic 1.1 GB -> 270 MB, the R8 wall); window [4p][10h][10w][64]
// = 51.2 KB -> 3 blocks/CU, one dispatch round. hipMemsetAsync(grid8)
// replaced by k_zero (rocclr fill kernel measured 51 GB/s -> ~50 us).

#define VN   40000
#define CIN  4
#define PN   32
#define SP2  40000
#define SP3  160000
#define HID  64
#define OUTC 256
#define EPSF 1e-5f

typedef __attribute__((ext_vector_type(8)))  short short8;
typedef __attribute__((ext_vector_type(16))) float f32x16;

__device__ inline unsigned short f2bf(float f) {
    unsigned u = __builtin_bit_cast(unsigned, f);
    return (unsigned short)((u + 0x7fffu + ((u >> 16) & 1u)) >> 16);
}
__device__ inline float bf2f(unsigned short h) {
    return __builtin_bit_cast(float, ((unsigned)h) << 16);
}
__device__ inline short8 ld8(const unsigned short* p) {
    return __builtin_bit_cast(short8, *reinterpret_cast<const uint4*>(p));
}

// ---- zero grid8 (2.56 MB): one uint4 per thread ----
__global__ __launch_bounds__(256) void k_zero(uint4* __restrict__ p) {
    p[blockIdx.x * 256 + threadIdx.x] = make_uint4(0, 0, 0, 0);
}

// ---- prep: scatter-mean + all three weight packs, one kernel ----
__global__ __launch_bounds__(256) void k_prep(const float* __restrict__ vox,
                                              const int* __restrict__ idx,
                                              const float* __restrict__ W1,
                                              const float* __restrict__ W2,
                                              const float* __restrict__ WH,
                                              unsigned short* __restrict__ G8,
                                              unsigned short* __restrict__ A1,
                                              unsigned short* __restrict__ A2,
                                              unsigned short* __restrict__ AH) {
    int i = blockIdx.x * 256 + threadIdx.x;
    if (i < VN) {
        int v = i;
        const float4* p = reinterpret_cast<const float4*>(vox + (size_t)v * CIN * PN);
        float m[4];
#pragma unroll
        for (int c = 0; c < 4; ++c) {
            float s = 0.f;
#pragma unroll
            for (int q = 0; q < PN / 4; ++q) {
                float4 r = p[c * (PN / 4) + q];
                s += (r.x + r.y) + (r.z + r.w);
            }
            m[c] = s * (1.f / PN);
        }
        int x = idx[v * 3 + 0], y = idx[v * 3 + 1], z = idx[v * 3 + 2];
        size_t sp = (size_t)z * SP2 + y * 200 + x;
        uint2 o;
        o.x = (unsigned)f2bf(m[0]) | ((unsigned)f2bf(m[1]) << 16);
        o.y = (unsigned)f2bf(m[2]) | ((unsigned)f2bf(m[3]) << 16);
        *reinterpret_cast<uint2*>(G8 + sp * 8) = o;   // ci 4..7 stay zero (k_zero)
        return;
    }
    int k = i - VN;
    if (k < 14336) {           // conv1 W: [s14][mt2][lane][8]
        int j = k & 7, l = (k >> 3) & 63, mt = (k >> 9) & 1, s = k >> 10;
        int co = mt * 32 + (l & 31);
        int tap = s * 2 + (l >> 5);
        float v = 0.f;
        if (tap < 27 && j < 4) v = W1[(co * 4 + j) * 27 + tap];
        A1[k] = f2bf(v);
    } else if (k < 124928) {   // conv2 W: [tap27][cib4][mt2][lane][8]
        int k2 = k - 14336;
        int j = k2 & 7, l = (k2 >> 3) & 63, mt = (k2 >> 9) & 1, cib = (k2 >> 10) & 3, tap = k2 >> 12;
        int co = mt * 32 + (l & 31);
        int ci = cib * 16 + (l >> 5) * 8 + j;
        A2[k2] = f2bf(W2[(co * 64 + ci) * 27 + tap]);
    } else if (k < 190464) {   // head W: [cib16][mtg8][lane][8]
        int k3 = k - 124928;
        int j = k3 & 7, l = (k3 >> 3) & 63, mtg = (k3 >> 9) & 7, cib = k3 >> 12;
        int o = mtg * 32 + (l & 31);
        int kp = cib * 16 + (l >> 5) * 8 + j;
        int hid = kp & 63, d = kp >> 6;
        AH[k3] = f2bf(WH[o * 256 + hid * 4 + d]);
    }
}

// ---- conv1 MFMA 32x32x16: grid8 [sp][8ci] -> y1b bf16 [sp][64co] (+bias) ----
// Block: 4h x 8w x 4d, 2 waves. Window [6p][6h][10w][8ci], zero-padded d-halo.
__global__ __launch_bounds__(128) void k_conv1m(const unsigned short* __restrict__ G8,
                                                const unsigned short* __restrict__ A1,
                                                const float* __restrict__ B1,
                                                unsigned short* __restrict__ Y1) {
    __shared__ unsigned short win[360 * 8];
    int bh = blockIdx.x / 25, bw = blockIdx.x % 25;
    int h0 = bh * 4, w0 = bw * 8;
    int t = threadIdx.x;
    for (int e = t; e < 360; e += 128) {
        int p6 = e / 60, rr = e % 60;
        int hh = rr / 10, ww = rr % 10;
        int ps = p6 - 1, hg = h0 + hh - 1, wg = w0 + ww - 1;
        uint4 v = make_uint4(0, 0, 0, 0);
        if ((unsigned)ps < 4u && (unsigned)hg < 200u && (unsigned)wg < 200u)
            v = *reinterpret_cast<const uint4*>(G8 + (size_t)(ps * SP2 + hg * 200 + wg) * 8);
        *reinterpret_cast<uint4*>(win + e * 8) = v;
    }
    __syncthreads();
    int wv = t >> 6, l = t & 63;
    int hi = l >> 5, h_off = (l & 31) >> 3, w = l & 7;
    int d0 = wv * 2;
    f32x16 acc[2][2] = {};   // [mt][nt]
#pragma unroll
    for (int s = 0; s < 14; ++s) {
        int tap = s * 2 + hi; if (tap > 26) tap = 26;   // A zero for tap 27
        int kd = tap / 9, r9 = tap % 9, kh = r9 / 3, kw = r9 % 3;
        const uint4* ap = reinterpret_cast<const uint4*>(A1) + (s * 2) * 64 + l;
        short8 a0 = __builtin_bit_cast(short8, ap[0]);
        short8 a1 = __builtin_bit_cast(short8, ap[64]);
#pragma unroll
        for (int nt = 0; nt < 2; ++nt) {
            int cell = (d0 + nt + kd) * 60 + (h_off + kh) * 10 + (w + kw);
            short8 bfr = ld8(win + cell * 8);
            acc[0][nt] = __builtin_amdgcn_mfma_f32_32x32x16_bf16(a0, bfr, acc[0][nt], 0, 0, 0);
            acc[1][nt] = __builtin_amdgcn_mfma_f32_32x32x16_bf16(a1, bfr, acc[1][nt], 0, 0, 0);
        }
    }
    const float4* Bv = reinterpret_cast<const float4*>(B1);
#pragma unroll
    for (int mt = 0; mt < 2; ++mt) {
#pragma unroll
        for (int nt = 0; nt < 2; ++nt) {
            int sp = (d0 + nt) * SP2 + (h0 + h_off) * 200 + (w0 + w);
#pragma unroll
            for (int rq = 0; rq < 4; ++rq) {
                int co0 = mt * 32 + rq * 8 + hi * 4;
                float4 bb = Bv[co0 >> 2];
                uint2 o;
                o.x = (unsigned)f2bf(acc[mt][nt][rq * 4 + 0] + bb.x) |
                      ((unsigned)f2bf(acc[mt][nt][rq * 4 + 1] + bb.y) << 16);
                o.y = (unsigned)f2bf(acc[mt][nt][rq * 4 + 2] + bb.z) |
                      ((unsigned)f2bf(acc[mt][nt][rq * 4 + 3] + bb.w) << 16);
                *reinterpret_cast<uint2*>(Y1 + (size_t)sp * 64 + co0) = o;
            }
        }
    }
}

// ---- conv2 MFMA 32x32x16: y1b (BN1+ReLU fused on stage) -> y2b (+bias) ----
// R9: block = 8h x 8w x 4d (625 blocks), window [4p][10h][10w][64ci] 128-B
// XOR cells, 51.2 KB -> 3 blocks/CU. 4 waves: wave = (co-half ch, d-pair d0).
// Each wave streams only its co-half of A2 (108 KB): A-L2 traffic /4 vs R8.
// Per A-frag: up to 4 MFMA (2 d-planes x 2 h-groups).
__global__ __launch_bounds__(256, 3) void k_conv2m(const unsigned short* __restrict__ X,
                                                   const unsigned short* __restrict__ A2,
                                                   const float* __restrict__ AB1,
                                                   const float* __restrict__ B2,
                                                   unsigned short* __restrict__ Y2) {
    __shared__ unsigned short win[400 * 64];
    int bh = blockIdx.x / 25, bw = blockIdx.x % 25;
    int h0 = bh * 8, w0 = bw * 8;
    int t = threadIdx.x;
    int s8 = (t & 7) * 8;      // this thread's fixed 8-channel chunk
    float a8[8], b8[8];
#pragma unroll
    for (int j = 0; j < 8; ++j) { a8[j] = AB1[s8 + j]; b8[j] = AB1[64 + s8 + j]; }
#pragma unroll
    for (int i = 0; i < 13; ++i) {
        int cell = i * 32 + (t >> 3);
        if (cell < 400) {
            int p = cell / 100, rr = cell % 100;
            int hh = rr / 10, ww = rr % 10;
            int hg = h0 + hh - 1, wg = w0 + ww - 1;
            uint4 st = make_uint4(0, 0, 0, 0);
            if ((unsigned)hg < 200u && (unsigned)wg < 200u) {
                uint4 raw = *reinterpret_cast<const uint4*>(X + (size_t)(p * SP2 + hg * 200 + wg) * 64 + s8);
                unsigned r[4] = {raw.x, raw.y, raw.z, raw.w};
                unsigned q[4];
#pragma unroll
                for (int k = 0; k < 4; ++k) {
                    float lo = bf2f((unsigned short)(r[k] & 0xffff));
                    float hv = bf2f((unsigned short)(r[k] >> 16));
                    lo = fmaxf(fmaf(a8[k * 2], lo, b8[k * 2]), 0.f);
                    hv = fmaxf(fmaf(a8[k * 2 + 1], hv, b8[k * 2 + 1]), 0.f);
                    q[k] = (unsigned)f2bf(lo) | ((unsigned)f2bf(hv) << 16);
                }
                st = make_uint4(q[0], q[1], q[2], q[3]);
            }
            int slot = (t & 7) ^ (cell & 7);
            *reinterpret_cast<uint4*>(win + cell * 64 + slot * 8) = st;
        }
    }
    __syncthreads();
    int wv = t >> 6, l = t & 63;
    int hi = l >> 5, hb = (l & 31) >> 3, w = l & 7;
    int ch = wv & 1;           // co-half this wave owns
    int d0 = (wv >> 1) * 2;    // d-pair this wave owns
    f32x16 acc[2][2] = {};     // [nt(d-plane)][ng(h-group)]
    for (int kd = 0; kd < 3; ++kd) {
        int p0 = d0 + kd - 1;              // plane for nt=0
        bool v0 = (unsigned)p0 < 4u;       // wave-uniform
        bool v1 = (unsigned)(p0 + 1) < 4u;
#pragma unroll
        for (int khw = 0; khw < 9; ++khw) {
            int kh = khw / 3, kw = khw % 3;
            int tap = kd * 9 + khw;
            int rc = (hb + kh) * 10 + (w + kw);   // ng=0 row-col
#pragma unroll
            for (int cib = 0; cib < 4; ++cib) {
                const uint4* ap = reinterpret_cast<const uint4*>(A2) + (((tap * 4 + cib) * 2) + ch) * 64 + l;
                short8 a = __builtin_bit_cast(short8, ap[0]);
                int kch = cib * 2 + hi;
                if (v0) {
                    int c0 = p0 * 100 + rc;
                    int c1 = c0 + 40;
                    short8 b0 = ld8(win + c0 * 64 + ((kch ^ (c0 & 7)) << 3));
                    short8 b1 = ld8(win + c1 * 64 + ((kch ^ (c1 & 7)) << 3));
                    acc[0][0] = __builtin_amdgcn_mfma_f32_32x32x16_bf16(a, b0, acc[0][0], 0, 0, 0);
                    acc[0][1] = __builtin_amdgcn_mfma_f32_32x32x16_bf16(a, b1, acc[0][1], 0, 0, 0);
                }
                if (v1) {
                    int c0 = (p0 + 1) * 100 + rc;
                    int c1 = c0 + 40;
                    short8 b0 = ld8(win + c0 * 64 + ((kch ^ (c0 & 7)) << 3));
                    short8 b1 = ld8(win + c1 * 64 + ((kch ^ (c1 & 7)) << 3));
                    acc[1][0] = __builtin_amdgcn_mfma_f32_32x32x16_bf16(a, b0, acc[1][0], 0, 0, 0);
                    acc[1][1] = __builtin_amdgcn_mfma_f32_32x32x16_bf16(a, b1, acc[1][1], 0, 0, 0);
                }
            }
        }
    }
    const float4* Bv = reinterpret_cast<const float4*>(B2);
#pragma unroll
    for (int nt = 0; nt < 2; ++nt) {
#pragma unroll
        for (int ng = 0; ng < 2; ++ng) {
            int sp = (d0 + nt) * SP2 + (h0 + hb + ng * 4) * 200 + (w0 + w);
#pragma unroll
            for (int rq = 0; rq < 4; ++rq) {
                int co0 = ch * 32 + rq * 8 + hi * 4;
                float4 bb = Bv[co0 >> 2];
                uint2 o;
                o.x = (unsigned)f2bf(acc[nt][ng][rq * 4 + 0] + bb.x) |
                      ((unsigned)f2bf(acc[nt][ng][rq * 4 + 1] + bb.y) << 16);
                o.y = (unsigned)f2bf(acc[nt][ng][rq * 4 + 2] + bb.z) |
                      ((unsigned)f2bf(acc[nt][ng][rq * 4 + 3] + bb.w) << 16);
                *reinterpret_cast<uint2*>(Y2 + (size_t)sp * 64 + co0) = o;
            }
        }
    }
}

// ---- BN stats over bf16 [sp][64]: 256 blocks x 625 rows, b128 reads ----
__global__ __launch_bounds__(256) void k_stats2p(const unsigned short* __restrict__ Y,
                                                 float* __restrict__ P) {
    int bid = blockIdx.x, t = threadIdx.x, wv = t >> 6, l = t & 63;
    int cg = l & 7, rsub = l >> 3;
    float s[8] = {}, q[8] = {};
    int rend = bid * 625 + 625;
    for (int r = bid * 625 + wv * 8 + rsub; r < rend; r += 32) {
        uint4 raw = *reinterpret_cast<const uint4*>(Y + (size_t)r * 64 + cg * 8);
        unsigned rr[4] = {raw.x, raw.y, raw.z, raw.w};
#pragma unroll
        for (int k = 0; k < 4; ++k) {
            float lo = bf2f((unsigned short)(rr[k] & 0xffff));
            float hv = bf2f((unsigned short)(rr[k] >> 16));
            s[2 * k] += lo;     q[2 * k] += lo * lo;
            s[2 * k + 1] += hv; q[2 * k + 1] += hv * hv;
        }
    }
#pragma unroll
    for (int k = 0; k < 8; ++k) {
#pragma unroll
        for (int m = 8; m < 64; m <<= 1) {
            s[k] += __shfl_xor(s[k], m);
            q[k] += __shfl_xor(q[k], m);
        }
    }
    __shared__ float ls[4][128];
    if (l < 8) {
#pragma unroll
        for (int k = 0; k < 8; ++k) {
            ls[wv][cg * 8 + k] = s[k];
            ls[wv][64 + cg * 8 + k] = q[k];
        }
    }
    __syncthreads();
    if (t < 128) P[bid * 128 + t] = ls[0][t] + ls[1][t] + ls[2][t] + ls[3][t];
}

// ---- stats finalize over 256 partials (1024 threads, one block) ----
__global__ __launch_bounds__(1024) void k_statsf(const float* __restrict__ P,
                                                 const float* __restrict__ G,
                                                 const float* __restrict__ BE,
                                                 float* __restrict__ AB) {
    __shared__ float red[8][128];
    int t = threadIdx.x, c = t & 127, grp = t >> 7;
    float S = 0.f;
    for (int b = grp; b < 256; b += 8) S += P[(size_t)b * 128 + c];
    red[grp][c] = S;
    __syncthreads();
    if (t < 128) {
        float v = 0.f;
#pragma unroll
        for (int g = 0; g < 8; ++g) v += red[g][t];
        red[0][t] = v;
    }
    __syncthreads();
    if (t < 64) {
        float m = red[0][t] * (1.f / SP3);
        float var = red[0][64 + t] * (1.f / SP3) - m * m;
        float a = G[t] * rsqrtf(var + EPSF);
        AB[t] = a; AB[64 + t] = BE[t] - m * a;
    }
}

// ---- head MFMA: 4 waves (co-half x col-half), BN2+ReLU fused on B-load ----
__global__ __launch_bounds__(256) void k_headm(const unsigned short* __restrict__ X,
                                               const unsigned short* __restrict__ AH,
                                               const float* __restrict__ AB2,
                                               const float* __restrict__ BH,
                                               float* __restrict__ O, int dup2) {
    __shared__ float sab[128];
    int t = threadIdx.x;
    if (t < 128) sab[t] = AB2[t];
    __syncthreads();
    int wv = t >> 6, l = t & 63, khalf = l >> 5;
    int coh = wv >> 1, colh = wv & 1;
    int sp = blockIdx.x * 64 + colh * 32 + (l & 31);
    f32x16 acc[4] = {};
#pragma unroll
    for (int cib = 0; cib < 16; ++cib) {
        int d = cib >> 2, ch0 = (cib & 3) * 16 + khalf * 8;
        uint4 raw = *(const uint4*)(X + ((size_t)(d * SP2 + sp)) * 64 + ch0);
        unsigned r[4] = {raw.x, raw.y, raw.z, raw.w}, qq[4];
#pragma unroll
        for (int k2 = 0; k2 < 4; ++k2) {
            int c0 = ch0 + k2 * 2;
            float lo = bf2f((unsigned short)(r[k2] & 0xffff));
            float hi = bf2f((unsigned short)(r[k2] >> 16));
            lo = fmaxf(fmaf(sab[c0], lo, sab[64 + c0]), 0.f);
            hi = fmaxf(fmaf(sab[c0 + 1], hi, sab[64 + c0 + 1]), 0.f);
            qq[k2] = (unsigned)f2bf(lo) | ((unsigned)f2bf(hi) << 16);
        }
        short8 bfr = __builtin_bit_cast(short8, make_uint4(qq[0], qq[1], qq[2], qq[3]));
#pragma unroll
        for (int mi = 0; mi < 4; ++mi) {
            const uint4* ap = (const uint4*)AH + (cib * 8 + coh * 4 + mi) * 64 + l;
            short8 afr = __builtin_bit_cast(short8, *ap);
            acc[mi] = __builtin_amdgcn_mfma_f32_32x32x16_bf16(afr, bfr, acc[mi], 0, 0, 0);
        }
    }
#pragma unroll
    for (int mi = 0; mi < 4; ++mi) {
#pragma unroll
        for (int rq = 0; rq < 4; ++rq) {
            int co0 = coh * 128 + mi * 32 + rq * 8 + khalf * 4;
            float4 bb = *(const float4*)(BH + co0);
#pragma unroll
            for (int j = 0; j < 4; ++j) {
                float val = acc[mi][rq * 4 + j] + ((const float*)&bb)[j];
                size_t o = (size_t)(co0 + j) * SP2 + sp;
                O[o] = val;
                if (dup2) O[10240000 + o] = val;
            }
        }
    }
}

// ---- duplicate batch0 -> batch1 (fallback mode only) ----
__global__ __launch_bounds__(256) void k_dup(float* __restrict__ O) {
    int i = blockIdx.x * 256 + threadIdx.x;
    float4* p = reinterpret_cast<float4*>(O);
    p[OUTC * SP2 / 4 + i] = p[i];
}

extern "C" void kernel_launch(void* const* d_in, const int* in_sizes, int n_in,
                              void* d_out, int out_size, void* d_ws, size_t ws_size,
                              hipStream_t stream) {
    const float* vox = (const float*)d_in[0];
    const int*   idx = (const int*)d_in[1];
    const float* w1  = (const float*)d_in[3];
    const float* b1  = (const float*)d_in[4];
    const float* g1  = (const float*)d_in[5];
    const float* be1 = (const float*)d_in[6];
    const float* w2  = (const float*)d_in[7];
    const float* b2  = (const float*)d_in[8];
    const float* g2  = (const float*)d_in[9];
    const float* be2 = (const float*)d_in[10];
    const float* wh  = (const float*)d_in[11];
    const float* bh  = (const float*)d_in[12];

    float* out = (float*)d_out;
    char* ws = (char*)d_ws;
    unsigned short* grid8  = (unsigned short*)ws;                 // 2,560,000 B
    float*          ab1    = (float*)(ws + 2560000);              // 512 B
    float*          ab2    = (float*)(ws + 2560512);              // 512 B
    float*          part   = (float*)(ws + 2561024);              // 131,072 B (256*128*4)
    unsigned short* apack1 = (unsigned short*)(ws + 2692096);     // 28,672 B
    unsigned short* apack2 = (unsigned short*)(ws + 2720768);     // 221,184 B
    unsigned short* apackh = (unsigned short*)(ws + 2941952);     // 131,072 B

    bool ws_mode = ws_size >= 44033024u;
    unsigned short* y1b, * y2b;
    if (ws_mode) {
        y1b = (unsigned short*)(ws + 3073024);
        y2b = (unsigned short*)(ws + 23553024);
    } else {
        y1b = (unsigned short*)(out + 10240000);
        y2b = y1b + 10240000;
    }

    k_zero<<<625, 256, 0, stream>>>((uint4*)grid8);   // 625*256*16 B = 2.56 MB
    k_prep<<<901, 256, 0, stream>>>(vox, idx, w1, w2, wh, grid8, apack1, apack2, apackh);
    k_conv1m<<<1250, 128, 0, stream>>>(grid8, apack1, b1, y1b);
    k_stats2p<<<256, 256, 0, stream>>>(y1b, part);
    k_statsf<<<1, 1024, 0, stream>>>(part, g1, be1, ab1);
    k_conv2m<<<625, 256, 0, stream>>>(y1b, apack2, ab1, b2, y2b);
    k_stats2p<<<256, 256, 0, stream>>>(y2b, part);
    k_statsf<<<1, 1024, 0, stream>>>(part, g2, be2, ab2);
    k_headm<<<625, 256, 0, stream>>>(y2b, apackh, ab2, bh, out, ws_mode ? 1 : 0);
    if (!ws_mode)
        k_dup<<<10000, 256, 0, stream>>>(out);
}

// Round 10
// 137.100 us; speedup vs baseline: 1.0500x; 1.0500x over previous
//
#include <hip/hip_runtime.h>

// VoxelNet MI355X. Batch collapsed to 1 (identical slots; BN stats invariant).
// conv1/conv2/head all bf16 MFMA 32x32x16, fp32 accumulate, LDS-window
// implicit GEMM. R10: conv2m = R8 geometry (best measured: [4p][6h][10w]
// 128-B XOR cells, 30.72 KB, 5 blk/CU, 50x25 grid, 4 waves each owning one
// d-plane) + MANUAL SOFTWARE PIPELINE of the flat 36-iter (khw x cib) body:
// iter i+1's 2 A-loads + B-ds_read issue before iter i's MFMAs (R8 measured
// VGPR=48 -> compiler did no pipelining; latency-bound at MfmaUtil 23%).

#define VN   40000
#define CIN  4
#define PN   32
#define SP2  40000
#define SP3  160000
#define HID  64
#define OUTC 256
#define EPSF 1e-5f

typedef __attribute__((ext_vector_type(8)))  short short8;
typedef __attribute__((ext_vector_type(16))) float f32x16;

__device__ inline unsigned short f2bf(float f) {
    unsigned u = __builtin_bit_cast(unsigned, f);
    return (unsigned short)((u + 0x7fffu + ((u >> 16) & 1u)) >> 16);
}
__device__ inline float bf2f(unsigned short h) {
    return __builtin_bit_cast(float, ((unsigned)h) << 16);
}
__device__ inline short8 ld8(const unsigned short* p) {
    return __builtin_bit_cast(short8, *reinterpret_cast<const uint4*>(p));
}

// ---- zero grid8 (2.56 MB): one uint4 per thread ----
__global__ __launch_bounds__(256) void k_zero(uint4* __restrict__ p) {
    p[blockIdx.x * 256 + threadIdx.x] = make_uint4(0, 0, 0, 0);
}

// ---- prep: scatter-mean + all three weight packs, one kernel ----
__global__ __launch_bounds__(256) void k_prep(const float* __restrict__ vox,
                                              const int* __restrict__ idx,
                                              const float* __restrict__ W1,
                                              const float* __restrict__ W2,
                                              const float* __restrict__ WH,
                                              unsigned short* __restrict__ G8,
                                              unsigned short* __restrict__ A1,
                                              unsigned short* __restrict__ A2,
                                              unsigned short* __restrict__ AH) {
    int i = blockIdx.x * 256 + threadIdx.x;
    if (i < VN) {
        int v = i;
        const float4* p = reinterpret_cast<const float4*>(vox + (size_t)v * CIN * PN);
        float m[4];
#pragma unroll
        for (int c = 0; c < 4; ++c) {
            float s = 0.f;
#pragma unroll
            for (int q = 0; q < PN / 4; ++q) {
                float4 r = p[c * (PN / 4) + q];
                s += (r.x + r.y) + (r.z + r.w);
            }
            m[c] = s * (1.f / PN);
        }
        int x = idx[v * 3 + 0], y = idx[v * 3 + 1], z = idx[v * 3 + 2];
        size_t sp = (size_t)z * SP2 + y * 200 + x;
        uint2 o;
        o.x = (unsigned)f2bf(m[0]) | ((unsigned)f2bf(m[1]) << 16);
        o.y = (unsigned)f2bf(m[2]) | ((unsigned)f2bf(m[3]) << 16);
        *reinterpret_cast<uint2*>(G8 + sp * 8) = o;   // ci 4..7 stay zero (k_zero)
        return;
    }
    int k = i - VN;
    if (k < 14336) {           // conv1 W: [s14][mt2][lane][8]
        int j = k & 7, l = (k >> 3) & 63, mt = (k >> 9) & 1, s = k >> 10;
        int co = mt * 32 + (l & 31);
        int tap = s * 2 + (l >> 5);
        float v = 0.f;
        if (tap < 27 && j < 4) v = W1[(co * 4 + j) * 27 + tap];
        A1[k] = f2bf(v);
    } else if (k < 124928) {   // conv2 W: [tap27][cib4][mt2][lane][8]
        int k2 = k - 14336;
        int j = k2 & 7, l = (k2 >> 3) & 63, mt = (k2 >> 9) & 1, cib = (k2 >> 10) & 3, tap = k2 >> 12;
        int co = mt * 32 + (l & 31);
        int ci = cib * 16 + (l >> 5) * 8 + j;
        A2[k2] = f2bf(W2[(co * 64 + ci) * 27 + tap]);
    } else if (k < 190464) {   // head W: [cib16][mtg8][lane][8]
        int k3 = k - 124928;
        int j = k3 & 7, l = (k3 >> 3) & 63, mtg = (k3 >> 9) & 7, cib = k3 >> 12;
        int o = mtg * 32 + (l & 31);
        int kp = cib * 16 + (l >> 5) * 8 + j;
        int hid = kp & 63, d = kp >> 6;
        AH[k3] = f2bf(WH[o * 256 + hid * 4 + d]);
    }
}

// ---- conv1 MFMA 32x32x16: grid8 [sp][8ci] -> y1b bf16 [sp][64co] (+bias) ----
// Block: 4h x 8w x 4d, 2 waves. Window [6p][6h][10w][8ci], zero-padded d-halo.
__global__ __launch_bounds__(128) void k_conv1m(const unsigned short* __restrict__ G8,
                                                const unsigned short* __restrict__ A1,
                                                const float* __restrict__ B1,
                                                unsigned short* __restrict__ Y1) {
    __shared__ unsigned short win[360 * 8];
    int bh = blockIdx.x / 25, bw = blockIdx.x % 25;
    int h0 = bh * 4, w0 = bw * 8;
    int t = threadIdx.x;
    for (int e = t; e < 360; e += 128) {
        int p6 = e / 60, rr = e % 60;
        int hh = rr / 10, ww = rr % 10;
        int ps = p6 - 1, hg = h0 + hh - 1, wg = w0 + ww - 1;
        uint4 v = make_uint4(0, 0, 0, 0);
        if ((unsigned)ps < 4u && (unsigned)hg < 200u && (unsigned)wg < 200u)
            v = *reinterpret_cast<const uint4*>(G8 + (size_t)(ps * SP2 + hg * 200 + wg) * 8);
        *reinterpret_cast<uint4*>(win + e * 8) = v;
    }
    __syncthreads();
    int wv = t >> 6, l = t & 63;
    int hi = l >> 5, h_off = (l & 31) >> 3, w = l & 7;
    int d0 = wv * 2;
    f32x16 acc[2][2] = {};   // [mt][nt]
#pragma unroll
    for (int s = 0; s < 14; ++s) {
        int tap = s * 2 + hi; if (tap > 26) tap = 26;   // A zero for tap 27
        int kd = tap / 9, r9 = tap % 9, kh = r9 / 3, kw = r9 % 3;
        const uint4* ap = reinterpret_cast<const uint4*>(A1) + (s * 2) * 64 + l;
        short8 a0 = __builtin_bit_cast(short8, ap[0]);
        short8 a1 = __builtin_bit_cast(short8, ap[64]);
#pragma unroll
        for (int nt = 0; nt < 2; ++nt) {
            int cell = (d0 + nt + kd) * 60 + (h_off + kh) * 10 + (w + kw);
            short8 bfr = ld8(win + cell * 8);
            acc[0][nt] = __builtin_amdgcn_mfma_f32_32x32x16_bf16(a0, bfr, acc[0][nt], 0, 0, 0);
            acc[1][nt] = __builtin_amdgcn_mfma_f32_32x32x16_bf16(a1, bfr, acc[1][nt], 0, 0, 0);
        }
    }
    const float4* Bv = reinterpret_cast<const float4*>(B1);
#pragma unroll
    for (int mt = 0; mt < 2; ++mt) {
#pragma unroll
        for (int nt = 0; nt < 2; ++nt) {
            int sp = (d0 + nt) * SP2 + (h0 + h_off) * 200 + (w0 + w);
#pragma unroll
            for (int rq = 0; rq < 4; ++rq) {
                int co0 = mt * 32 + rq * 8 + hi * 4;
                float4 bb = Bv[co0 >> 2];
                uint2 o;
                o.x = (unsigned)f2bf(acc[mt][nt][rq * 4 + 0] + bb.x) |
                      ((unsigned)f2bf(acc[mt][nt][rq * 4 + 1] + bb.y) << 16);
                o.y = (unsigned)f2bf(acc[mt][nt][rq * 4 + 2] + bb.z) |
                      ((unsigned)f2bf(acc[mt][nt][rq * 4 + 3] + bb.w) << 16);
                *reinterpret_cast<uint2*>(Y1 + (size_t)sp * 64 + co0) = o;
            }
        }
    }
}

// ---- conv2 MFMA 32x32x16: y1b (BN1+ReLU fused on stage) -> y2b (+bias) ----
// R8 geometry: [4p][6h][10w][64ci] 128-B XOR cells, 30.72 KB, 5 blk/CU,
// 50x25 grid (1250 blocks, one round), 4 waves each owning one d-plane.
// R10: flat 36-iter (khw*4+cib) body with 1-deep manual software pipeline.
__global__ __launch_bounds__(256, 5) void k_conv2m(const unsigned short* __restrict__ X,
                                                   const unsigned short* __restrict__ A2,
                                                   const float* __restrict__ AB1,
                                                   const float* __restrict__ B2,
                                                   unsigned short* __restrict__ Y2) {
    __shared__ unsigned short win[240 * 64];
    int bh = blockIdx.x / 25, bw = blockIdx.x % 25;
    int h0 = bh * 4, w0 = bw * 8;
    int t = threadIdx.x;
    int s8 = (t & 7) * 8;      // this thread's fixed 8-channel chunk
    float a8[8], b8[8];
#pragma unroll
    for (int j = 0; j < 8; ++j) { a8[j] = AB1[s8 + j]; b8[j] = AB1[64 + s8 + j]; }
#pragma unroll
    for (int i = 0; i < 8; ++i) {
        int cell = i * 32 + (t >> 3);
        if (cell < 240) {
            int p = cell / 60, rr = cell % 60;
            int hh = rr / 10, ww = rr % 10;
            int hg = h0 + hh - 1, wg = w0 + ww - 1;
            uint4 st = make_uint4(0, 0, 0, 0);
            if ((unsigned)hg < 200u && (unsigned)wg < 200u) {
                uint4 raw = *reinterpret_cast<const uint4*>(X + (size_t)(p * SP2 + hg * 200 + wg) * 64 + s8);
                unsigned r[4] = {raw.x, raw.y, raw.z, raw.w};
                unsigned q[4];
#pragma unroll
                for (int k = 0; k < 4; ++k) {
                    float lo = bf2f((unsigned short)(r[k] & 0xffff));
                    float hv = bf2f((unsigned short)(r[k] >> 16));
                    lo = fmaxf(fmaf(a8[k * 2], lo, b8[k * 2]), 0.f);
                    hv = fmaxf(fmaf(a8[k * 2 + 1], hv, b8[k * 2 + 1]), 0.f);
                    q[k] = (unsigned)f2bf(lo) | ((unsigned)f2bf(hv) << 16);
                }
                st = make_uint4(q[0], q[1], q[2], q[3]);
            }
            int slot = (t & 7) ^ (cell & 7);
            *reinterpret_cast<uint4*>(win + cell * 64 + slot * 8) = st;
        }
    }
    __syncthreads();
    int wv = t >> 6, l = t & 63;
    int hi = l >> 5, hb = (l & 31) >> 3, w = l & 7;
    int d = wv;                 // each wave: one output d-plane
    const uint4* A2v = reinterpret_cast<const uint4*>(A2);
    f32x16 acc[2] = {};         // [mt]
    for (int kd = 0; kd < 3; ++kd) {
        int p = d + kd - 1;
        if ((unsigned)p >= 4u) continue;    // wave-uniform skip
        int tap0 = kd * 9;
        // prologue: operands for it = 0 (khw=0 -> kh=0,kw=0; cib=0)
        const uint4* ap0 = A2v + ((tap0 * 4 + 0) * 2) * 64 + l;
        uint4 ra0 = ap0[0];
        uint4 ra1 = ap0[64];
        int cell_p = p * 60 + hb * 10 + w;
        uint4 rb = *reinterpret_cast<const uint4*>(win + cell_p * 64 + ((hi ^ (cell_p & 7)) << 3));
#pragma unroll
        for (int it = 0; it < 36; ++it) {
            uint4 na0 = ra0, na1 = ra1, nb = rb;
            if (it + 1 < 36) {              // compile-time folded
                int nit = it + 1;
                int nkhw = nit >> 2, ncib = nit & 3;
                int nkh = nkhw / 3, nkw = nkhw % 3;
                const uint4* ap = A2v + (((tap0 + nkhw) * 4 + ncib) * 2) * 64 + l;
                na0 = ap[0];
                na1 = ap[64];
                int ncell = p * 60 + (hb + nkh) * 10 + (w + nkw);
                int nkch = ncib * 2 + hi;
                nb = *reinterpret_cast<const uint4*>(win + ncell * 64 + ((nkch ^ (ncell & 7)) << 3));
            }
            short8 a0 = __builtin_bit_cast(short8, ra0);
            short8 a1 = __builtin_bit_cast(short8, ra1);
            short8 b  = __builtin_bit_cast(short8, rb);
            acc[0] = __builtin_amdgcn_mfma_f32_32x32x16_bf16(a0, b, acc[0], 0, 0, 0);
            acc[1] = __builtin_amdgcn_mfma_f32_32x32x16_bf16(a1, b, acc[1], 0, 0, 0);
            ra0 = na0; ra1 = na1; rb = nb;
        }
    }
    const float4* Bv = reinterpret_cast<const float4*>(B2);
    int sp = d * SP2 + (h0 + hb) * 200 + (w0 + w);
#pragma unroll
    for (int mt = 0; mt < 2; ++mt) {
#pragma unroll
        for (int rq = 0; rq < 4; ++rq) {
            int co0 = mt * 32 + rq * 8 + hi * 4;
            float4 bb = Bv[co0 >> 2];
            uint2 o;
            o.x = (unsigned)f2bf(acc[mt][rq * 4 + 0] + bb.x) |
                  ((unsigned)f2bf(acc[mt][rq * 4 + 1] + bb.y) << 16);
            o.y = (unsigned)f2bf(acc[mt][rq * 4 + 2] + bb.z) |
                  ((unsigned)f2bf(acc[mt][rq * 4 + 3] + bb.w) << 16);
            *reinterpret_cast<uint2*>(Y2 + (size_t)sp * 64 + co0) = o;
        }
    }
}

// ---- BN stats over bf16 [sp][64]: 256 blocks x 625 rows, b128 reads ----
__global__ __launch_bounds__(256) void k_stats2p(const unsigned short* __restrict__ Y,
                                                 float* __restrict__ P) {
    int bid = blockIdx.x, t = threadIdx.x, wv = t >> 6, l = t & 63;
    int cg = l & 7, rsub = l >> 3;
    float s[8] = {}, q[8] = {};
    int rend = bid * 625 + 625;
    for (int r = bid * 625 + wv * 8 + rsub; r < rend; r += 32) {
        uint4 raw = *reinterpret_cast<const uint4*>(Y + (size_t)r * 64 + cg * 8);
        unsigned rr[4] = {raw.x, raw.y, raw.z, raw.w};
#pragma unroll
        for (int k = 0; k < 4; ++k) {
            float lo = bf2f((unsigned short)(rr[k] & 0xffff));
            float hv = bf2f((unsigned short)(rr[k] >> 16));
            s[2 * k] += lo;     q[2 * k] += lo * lo;
            s[2 * k + 1] += hv; q[2 * k + 1] += hv * hv;
        }
    }
#pragma unroll
    for (int k = 0; k < 8; ++k) {
#pragma unroll
        for (int m = 8; m < 64; m <<= 1) {
            s[k] += __shfl_xor(s[k], m);
            q[k] += __shfl_xor(q[k], m);
        }
    }
    __shared__ float ls[4][128];
    if (l < 8) {
#pragma unroll
        for (int k = 0; k < 8; ++k) {
            ls[wv][cg * 8 + k] = s[k];
            ls[wv][64 + cg * 8 + k] = q[k];
        }
    }
    __syncthreads();
    if (t < 128) P[bid * 128 + t] = ls[0][t] + ls[1][t] + ls[2][t] + ls[3][t];
}

// ---- stats finalize over 256 partials (1024 threads, one block) ----
__global__ __launch_bounds__(1024) void k_statsf(const float* __restrict__ P,
                                                 const float* __restrict__ G,
                                                 const float* __restrict__ BE,
                                                 float* __restrict__ AB) {
    __shared__ float red[8][128];
    int t = threadIdx.x, c = t & 127, grp = t >> 7;
    float S = 0.f;
    for (int b = grp; b < 256; b += 8) S += P[(size_t)b * 128 + c];
    red[grp][c] = S;
    __syncthreads();
    if (t < 128) {
        float v = 0.f;
#pragma unroll
        for (int g = 0; g < 8; ++g) v += red[g][t];
        red[0][t] = v;
    }
    __syncthreads();
    if (t < 64) {
        float m = red[0][t] * (1.f / SP3);
        float var = red[0][64 + t] * (1.f / SP3) - m * m;
        float a = G[t] * rsqrtf(var + EPSF);
        AB[t] = a; AB[64 + t] = BE[t] - m * a;
    }
}

// ---- head MFMA: 4 waves (co-half x col-half), BN2+ReLU fused on B-load ----
__global__ __launch_bounds__(256) void k_headm(const unsigned short* __restrict__ X,
                                               const unsigned short* __restrict__ AH,
                                               const float* __restrict__ AB2,
                                               const float* __restrict__ BH,
                                               float* __restrict__ O, int dup2) {
    __shared__ float sab[128];
    int t = threadIdx.x;
    if (t < 128) sab[t] = AB2[t];
    __syncthreads();
    int wv = t >> 6, l = t & 63, khalf = l >> 5;
    int coh = wv >> 1, colh = wv & 1;
    int sp = blockIdx.x * 64 + colh * 32 + (l & 31);
    f32x16 acc[4] = {};
#pragma unroll
    for (int cib = 0; cib < 16; ++cib) {
        int d = cib >> 2, ch0 = (cib & 3) * 16 + khalf * 8;
        uint4 raw = *(const uint4*)(X + ((size_t)(d * SP2 + sp)) * 64 + ch0);
        unsigned r[4] = {raw.x, raw.y, raw.z, raw.w}, qq[4];
#pragma unroll
        for (int k2 = 0; k2 < 4; ++k2) {
            int c0 = ch0 + k2 * 2;
            float lo = bf2f((unsigned short)(r[k2] & 0xffff));
            float hi = bf2f((unsigned short)(r[k2] >> 16));
            lo = fmaxf(fmaf(sab[c0], lo, sab[64 + c0]), 0.f);
            hi = fmaxf(fmaf(sab[c0 + 1], hi, sab[64 + c0 + 1]), 0.f);
            qq[k2] = (unsigned)f2bf(lo) | ((unsigned)f2bf(hi) << 16);
        }
        short8 bfr = __builtin_bit_cast(short8, make_uint4(qq[0], qq[1], qq[2], qq[3]));
#pragma unroll
        for (int mi = 0; mi < 4; ++mi) {
            const uint4* ap = (const uint4*)AH + (cib * 8 + coh * 4 + mi) * 64 + l;
            short8 afr = __builtin_bit_cast(short8, *ap);
            acc[mi] = __builtin_amdgcn_mfma_f32_32x32x16_bf16(afr, bfr, acc[mi], 0, 0, 0);
        }
    }
#pragma unroll
    for (int mi = 0; mi < 4; ++mi) {
#pragma unroll
        for (int rq = 0; rq < 4; ++rq) {
            int co0 = coh * 128 + mi * 32 + rq * 8 + khalf * 4;
            float4 bb = *(const float4*)(BH + co0);
#pragma unroll
            for (int j = 0; j < 4; ++j) {
                float val = acc[mi][rq * 4 + j] + ((const float*)&bb)[j];
                size_t o = (size_t)(co0 + j) * SP2 + sp;
                O[o] = val;
                if (dup2) O[10240000 + o] = val;
            }
        }
    }
}

// ---- duplicate batch0 -> batch1 (fallback mode only) ----
__global__ __launch_bounds__(256) void k_dup(float* __restrict__ O) {
    int i = blockIdx.x * 256 + threadIdx.x;
    float4* p = reinterpret_cast<float4*>(O);
    p[OUTC * SP2 / 4 + i] = p[i];
}

extern "C" void kernel_launch(void* const* d_in, const int* in_sizes, int n_in,
                              void* d_out, int out_size, void* d_ws, size_t ws_size,
                              hipStream_t stream) {
    const float* vox = (const float*)d_in[0];
    const int*   idx = (const int*)d_in[1];
    const float* w1  = (const float*)d_in[3];
    const float* b1  = (const float*)d_in[4];
    const float* g1  = (const float*)d_in[5];
    const float* be1 = (const float*)d_in[6];
    const float* w2  = (const float*)d_in[7];
    const float* b2  = (const float*)d_in[8];
    const float* g2  = (const float*)d_in[9];
    const float* be2 = (const float*)d_in[10];
    const float* wh  = (const float*)d_in[11];
    const float* bh  = (const float*)d_in[12];

    float* out = (float*)d_out;
    char* ws = (char*)d_ws;
    unsigned short* grid8  = (unsigned short*)ws;                 // 2,560,000 B
    float*          ab1    = (float*)(ws + 2560000);              // 512 B
    float*          ab2    = (float*)(ws + 2560512);              // 512 B
    float*          part   = (float*)(ws + 2561024);              // 131,072 B (256*128*4)
    unsigned short* apack1 = (unsigned short*)(ws + 2692096);     // 28,672 B
    unsigned short* apack2 = (unsigned short*)(ws + 2720768);     // 221,184 B
    unsigned short* apackh = (unsigned short*)(ws + 2941952);     // 131,072 B

    bool ws_mode = ws_size >= 44033024u;
    unsigned short* y1b, * y2b;
    if (ws_mode) {
        y1b = (unsigned short*)(ws + 3073024);
        y2b = (unsigned short*)(ws + 23553024);
    } else {
        y1b = (unsigned short*)(out + 10240000);
        y2b = y1b + 10240000;
    }

    k_zero<<<625, 256, 0, stream>>>((uint4*)grid8);   // 625*256*16 B = 2.56 MB
    k_prep<<<901, 256, 0, stream>>>(vox, idx, w1, w2, wh, grid8, apack1, apack2, apackh);
    k_conv1m<<<1250, 128, 0, stream>>>(grid8, apack1, b1, y1b);
    k_stats2p<<<256, 256, 0, stream>>>(y1b, part);
    k_statsf<<<1, 1024, 0, stream>>>(part, g1, be1, ab1);
    k_conv2m<<<1250, 256, 0, stream>>>(y1b, apack2, ab1, b2, y2b);
    k_stats2p<<<256, 256, 0, stream>>>(y2b, part);
    k_statsf<<<1, 1024, 0, stream>>>(part, g2, be2, ab2);
    k_headm<<<625, 256, 0, stream>>>(y2b, apackh, ab2, bh, out, ws_mode ? 1 : 0);
    if (!ws_mode)
        k_dup<<<10000, 256, 0, stream>>>(out);
}

// Round 11
// 135.909 us; speedup vs baseline: 1.0592x; 1.0088x over previous
//
#include <hip/hip_runtime.h>

// VoxelNet MI355X. Batch collapsed to 1 (identical slots; BN stats invariant).
// conv1/conv2/head all bf16 MFMA 32x32x16, fp32 accumulate, LDS-window
// implicit GEMM. R11: conv2m = R8 geometry ([4p][6h][10w] 128-B XOR cells,
// 30.72 KB, 5 blk/CU, 50x25 grid, 4 waves each owning one d-plane) with the
// K-loop restructured into per-tap WIDE BATCHES: 8 A-loads + 4 ds_reads
// materialized into arrays, then 8 MFMAs -- forces 8-deep MLP the compiler
// can't collapse (R10's rotating pipeline was coalesced away, VGPR=44).

#define VN   40000
#define CIN  4
#define PN   32
#define SP2  40000
#define SP3  160000
#define HID  64
#define OUTC 256
#define EPSF 1e-5f

typedef __attribute__((ext_vector_type(8)))  short short8;
typedef __attribute__((ext_vector_type(16))) float f32x16;

__device__ inline unsigned short f2bf(float f) {
    unsigned u = __builtin_bit_cast(unsigned, f);
    return (unsigned short)((u + 0x7fffu + ((u >> 16) & 1u)) >> 16);
}
__device__ inline float bf2f(unsigned short h) {
    return __builtin_bit_cast(float, ((unsigned)h) << 16);
}
__device__ inline short8 ld8(const unsigned short* p) {
    return __builtin_bit_cast(short8, *reinterpret_cast<const uint4*>(p));
}

// ---- zero grid8 (2.56 MB): one uint4 per thread ----
__global__ __launch_bounds__(256) void k_zero(uint4* __restrict__ p) {
    p[blockIdx.x * 256 + threadIdx.x] = make_uint4(0, 0, 0, 0);
}

// ---- prep: scatter-mean + all three weight packs, one kernel ----
__global__ __launch_bounds__(256) void k_prep(const float* __restrict__ vox,
                                              const int* __restrict__ idx,
                                              const float* __restrict__ W1,
                                              const float* __restrict__ W2,
                                              const float* __restrict__ WH,
                                              unsigned short* __restrict__ G8,
                                              unsigned short* __restrict__ A1,
                                              unsigned short* __restrict__ A2,
                                              unsigned short* __restrict__ AH) {
    int i = blockIdx.x * 256 + threadIdx.x;
    if (i < VN) {
        int v = i;
        const float4* p = reinterpret_cast<const float4*>(vox + (size_t)v * CIN * PN);
        float m[4];
#pragma unroll
        for (int c = 0; c < 4; ++c) {
            float s = 0.f;
#pragma unroll
            for (int q = 0; q < PN / 4; ++q) {
                float4 r = p[c * (PN / 4) + q];
                s += (r.x + r.y) + (r.z + r.w);
            }
            m[c] = s * (1.f / PN);
        }
        int x = idx[v * 3 + 0], y = idx[v * 3 + 1], z = idx[v * 3 + 2];
        size_t sp = (size_t)z * SP2 + y * 200 + x;
        uint2 o;
        o.x = (unsigned)f2bf(m[0]) | ((unsigned)f2bf(m[1]) << 16);
        o.y = (unsigned)f2bf(m[2]) | ((unsigned)f2bf(m[3]) << 16);
        *reinterpret_cast<uint2*>(G8 + sp * 8) = o;   // ci 4..7 stay zero (k_zero)
        return;
    }
    int k = i - VN;
    if (k < 14336) {           // conv1 W: [s14][mt2][lane][8]
        int j = k & 7, l = (k >> 3) & 63, mt = (k >> 9) & 1, s = k >> 10;
        int co = mt * 32 + (l & 31);
        int tap = s * 2 + (l >> 5);
        float v = 0.f;
        if (tap < 27 && j < 4) v = W1[(co * 4 + j) * 27 + tap];
        A1[k] = f2bf(v);
    } else if (k < 124928) {   // conv2 W: [tap27][cib4][mt2][lane][8]
        int k2 = k - 14336;
        int j = k2 & 7, l = (k2 >> 3) & 63, mt = (k2 >> 9) & 1, cib = (k2 >> 10) & 3, tap = k2 >> 12;
        int co = mt * 32 + (l & 31);
        int ci = cib * 16 + (l >> 5) * 8 + j;
        A2[k2] = f2bf(W2[(co * 64 + ci) * 27 + tap]);
    } else if (k < 190464) {   // head W: [cib16][mtg8][lane][8]
        int k3 = k - 124928;
        int j = k3 & 7, l = (k3 >> 3) & 63, mtg = (k3 >> 9) & 7, cib = k3 >> 12;
        int o = mtg * 32 + (l & 31);
        int kp = cib * 16 + (l >> 5) * 8 + j;
        int hid = kp & 63, d = kp >> 6;
        AH[k3] = f2bf(WH[o * 256 + hid * 4 + d]);
    }
}

// ---- conv1 MFMA 32x32x16: grid8 [sp][8ci] -> y1b bf16 [sp][64co] (+bias) ----
// Block: 4h x 8w x 4d, 2 waves. Window [6p][6h][10w][8ci], zero-padded d-halo.
__global__ __launch_bounds__(128) void k_conv1m(const unsigned short* __restrict__ G8,
                                                const unsigned short* __restrict__ A1,
                                                const float* __restrict__ B1,
                                                unsigned short* __restrict__ Y1) {
    __shared__ unsigned short win[360 * 8];
    int bh = blockIdx.x / 25, bw = blockIdx.x % 25;
    int h0 = bh * 4, w0 = bw * 8;
    int t = threadIdx.x;
    for (int e = t; e < 360; e += 128) {
        int p6 = e / 60, rr = e % 60;
        int hh = rr / 10, ww = rr % 10;
        int ps = p6 - 1, hg = h0 + hh - 1, wg = w0 + ww - 1;
        uint4 v = make_uint4(0, 0, 0, 0);
        if ((unsigned)ps < 4u && (unsigned)hg < 200u && (unsigned)wg < 200u)
            v = *reinterpret_cast<const uint4*>(G8 + (size_t)(ps * SP2 + hg * 200 + wg) * 8);
        *reinterpret_cast<uint4*>(win + e * 8) = v;
    }
    __syncthreads();
    int wv = t >> 6, l = t & 63;
    int hi = l >> 5, h_off = (l & 31) >> 3, w = l & 7;
    int d0 = wv * 2;
    f32x16 acc[2][2] = {};   // [mt][nt]
#pragma unroll
    for (int s = 0; s < 14; ++s) {
        int tap = s * 2 + hi; if (tap > 26) tap = 26;   // A zero for tap 27
        int kd = tap / 9, r9 = tap % 9, kh = r9 / 3, kw = r9 % 3;
        const uint4* ap = reinterpret_cast<const uint4*>(A1) + (s * 2) * 64 + l;
        short8 a0 = __builtin_bit_cast(short8, ap[0]);
        short8 a1 = __builtin_bit_cast(short8, ap[64]);
#pragma unroll
        for (int nt = 0; nt < 2; ++nt) {
            int cell = (d0 + nt + kd) * 60 + (h_off + kh) * 10 + (w + kw);
            short8 bfr = ld8(win + cell * 8);
            acc[0][nt] = __builtin_amdgcn_mfma_f32_32x32x16_bf16(a0, bfr, acc[0][nt], 0, 0, 0);
            acc[1][nt] = __builtin_amdgcn_mfma_f32_32x32x16_bf16(a1, bfr, acc[1][nt], 0, 0, 0);
        }
    }
    const float4* Bv = reinterpret_cast<const float4*>(B1);
#pragma unroll
    for (int mt = 0; mt < 2; ++mt) {
#pragma unroll
        for (int nt = 0; nt < 2; ++nt) {
            int sp = (d0 + nt) * SP2 + (h0 + h_off) * 200 + (w0 + w);
#pragma unroll
            for (int rq = 0; rq < 4; ++rq) {
                int co0 = mt * 32 + rq * 8 + hi * 4;
                float4 bb = Bv[co0 >> 2];
                uint2 o;
                o.x = (unsigned)f2bf(acc[mt][nt][rq * 4 + 0] + bb.x) |
                      ((unsigned)f2bf(acc[mt][nt][rq * 4 + 1] + bb.y) << 16);
                o.y = (unsigned)f2bf(acc[mt][nt][rq * 4 + 2] + bb.z) |
                      ((unsigned)f2bf(acc[mt][nt][rq * 4 + 3] + bb.w) << 16);
                *reinterpret_cast<uint2*>(Y1 + (size_t)sp * 64 + co0) = o;
            }
        }
    }
}

// ---- conv2 MFMA 32x32x16: y1b (BN1+ReLU fused on stage) -> y2b (+bias) ----
// R8 geometry; K-loop in per-tap wide batches: 8 A-loads + 4 ds_reads into
// explicit arrays, then 8 MFMAs. Accumulation order (cib asc) unchanged.
__global__ __launch_bounds__(256, 5) void k_conv2m(const unsigned short* __restrict__ X,
                                                   const unsigned short* __restrict__ A2,
                                                   const float* __restrict__ AB1,
                                                   const float* __restrict__ B2,
                                                   unsigned short* __restrict__ Y2) {
    __shared__ unsigned short win[240 * 64];
    int bh = blockIdx.x / 25, bw = blockIdx.x % 25;
    int h0 = bh * 4, w0 = bw * 8;
    int t = threadIdx.x;
    int s8 = (t & 7) * 8;      // this thread's fixed 8-channel chunk
    float a8[8], b8[8];
#pragma unroll
    for (int j = 0; j < 8; ++j) { a8[j] = AB1[s8 + j]; b8[j] = AB1[64 + s8 + j]; }
#pragma unroll
    for (int i = 0; i < 8; ++i) {
        int cell = i * 32 + (t >> 3);
        if (cell < 240) {
            int p = cell / 60, rr = cell % 60;
            int hh = rr / 10, ww = rr % 10;
            int hg = h0 + hh - 1, wg = w0 + ww - 1;
            uint4 st = make_uint4(0, 0, 0, 0);
            if ((unsigned)hg < 200u && (unsigned)wg < 200u) {
                uint4 raw = *reinterpret_cast<const uint4*>(X + (size_t)(p * SP2 + hg * 200 + wg) * 64 + s8);
                unsigned r[4] = {raw.x, raw.y, raw.z, raw.w};
                unsigned q[4];
#pragma unroll
                for (int k = 0; k < 4; ++k) {
                    float lo = bf2f((unsigned short)(r[k] & 0xffff));
                    float hv = bf2f((unsigned short)(r[k] >> 16));
                    lo = fmaxf(fmaf(a8[k * 2], lo, b8[k * 2]), 0.f);
                    hv = fmaxf(fmaf(a8[k * 2 + 1], hv, b8[k * 2 + 1]), 0.f);
                    q[k] = (unsigned)f2bf(lo) | ((unsigned)f2bf(hv) << 16);
                }
                st = make_uint4(q[0], q[1], q[2], q[3]);
            }
            int slot = (t & 7) ^ (cell & 7);
            *reinterpret_cast<uint4*>(win + cell * 64 + slot * 8) = st;
        }
    }
    __syncthreads();
    int wv = t >> 6, l = t & 63;
    int hi = l >> 5, hb = (l & 31) >> 3, w = l & 7;
    int d = wv;                 // each wave: one output d-plane
    const uint4* A2v = reinterpret_cast<const uint4*>(A2);
    f32x16 acc[2] = {};         // [mt]
    for (int kd = 0; kd < 3; ++kd) {
        int p = d + kd - 1;
        if ((unsigned)p >= 4u) continue;    // wave-uniform skip
        int tap0 = kd * 9;
#pragma unroll
        for (int khw = 0; khw < 9; ++khw) {
            int kh = khw / 3, kw = khw % 3;
            int tap = tap0 + khw;
            int cell = p * 60 + (hb + kh) * 10 + (w + kw);
            const uint4* apb = A2v + ((tap * 4) * 2) * 64 + l;
            // ---- wide batch: 8 independent A-loads ----
            uint4 Ar[8];
#pragma unroll
            for (int j = 0; j < 8; ++j) Ar[j] = apb[j * 64];
            // ---- 4 independent B ds_reads (same cell, different kch slot) ----
            uint4 Br[4];
#pragma unroll
            for (int cib = 0; cib < 4; ++cib) {
                int kch = cib * 2 + hi;
                Br[cib] = *reinterpret_cast<const uint4*>(win + cell * 64 + ((kch ^ (cell & 7)) << 3));
            }
            // ---- 8 MFMAs (cib ascending: same accumulation order) ----
#pragma unroll
            for (int cib = 0; cib < 4; ++cib) {
                short8 b = __builtin_bit_cast(short8, Br[cib]);
                acc[0] = __builtin_amdgcn_mfma_f32_32x32x16_bf16(
                    __builtin_bit_cast(short8, Ar[cib * 2]), b, acc[0], 0, 0, 0);
                acc[1] = __builtin_amdgcn_mfma_f32_32x32x16_bf16(
                    __builtin_bit_cast(short8, Ar[cib * 2 + 1]), b, acc[1], 0, 0, 0);
            }
        }
    }
    const float4* Bv = reinterpret_cast<const float4*>(B2);
    int sp = d * SP2 + (h0 + hb) * 200 + (w0 + w);
#pragma unroll
    for (int mt = 0; mt < 2; ++mt) {
#pragma unroll
        for (int rq = 0; rq < 4; ++rq) {
            int co0 = mt * 32 + rq * 8 + hi * 4;
            float4 bb = Bv[co0 >> 2];
            uint2 o;
            o.x = (unsigned)f2bf(acc[mt][rq * 4 + 0] + bb.x) |
                  ((unsigned)f2bf(acc[mt][rq * 4 + 1] + bb.y) << 16);
            o.y = (unsigned)f2bf(acc[mt][rq * 4 + 2] + bb.z) |
                  ((unsigned)f2bf(acc[mt][rq * 4 + 3] + bb.w) << 16);
            *reinterpret_cast<uint2*>(Y2 + (size_t)sp * 64 + co0) = o;
        }
    }
}

// ---- BN stats over bf16 [sp][64]: 256 blocks x 625 rows, b128 reads ----
__global__ __launch_bounds__(256) void k_stats2p(const unsigned short* __restrict__ Y,
                                                 float* __restrict__ P) {
    int bid = blockIdx.x, t = threadIdx.x, wv = t >> 6, l = t & 63;
    int cg = l & 7, rsub = l >> 3;
    float s[8] = {}, q[8] = {};
    int rend = bid * 625 + 625;
    for (int r = bid * 625 + wv * 8 + rsub; r < rend; r += 32) {
        uint4 raw = *reinterpret_cast<const uint4*>(Y + (size_t)r * 64 + cg * 8);
        unsigned rr[4] = {raw.x, raw.y, raw.z, raw.w};
#pragma unroll
        for (int k = 0; k < 4; ++k) {
            float lo = bf2f((unsigned short)(rr[k] & 0xffff));
            float hv = bf2f((unsigned short)(rr[k] >> 16));
            s[2 * k] += lo;     q[2 * k] += lo * lo;
            s[2 * k + 1] += hv; q[2 * k + 1] += hv * hv;
        }
    }
#pragma unroll
    for (int k = 0; k < 8; ++k) {
#pragma unroll
        for (int m = 8; m < 64; m <<= 1) {
            s[k] += __shfl_xor(s[k], m);
            q[k] += __shfl_xor(q[k], m);
        }
    }
    __shared__ float ls[4][128];
    if (l < 8) {
#pragma unroll
        for (int k = 0; k < 8; ++k) {
            ls[wv][cg * 8 + k] = s[k];
            ls[wv][64 + cg * 8 + k] = q[k];
        }
    }
    __syncthreads();
    if (t < 128) P[bid * 128 + t] = ls[0][t] + ls[1][t] + ls[2][t] + ls[3][t];
}

// ---- stats finalize over 256 partials (1024 threads, one block) ----
__global__ __launch_bounds__(1024) void k_statsf(const float* __restrict__ P,
                                                 const float* __restrict__ G,
                                                 const float* __restrict__ BE,
                                                 float* __restrict__ AB) {
    __shared__ float red[8][128];
    int t = threadIdx.x, c = t & 127, grp = t >> 7;
    float S = 0.f;
    for (int b = grp; b < 256; b += 8) S += P[(size_t)b * 128 + c];
    red[grp][c] = S;
    __syncthreads();
    if (t < 128) {
        float v = 0.f;
#pragma unroll
        for (int g = 0; g < 8; ++g) v += red[g][t];
        red[0][t] = v;
    }
    __syncthreads();
    if (t < 64) {
        float m = red[0][t] * (1.f / SP3);
        float var = red[0][64 + t] * (1.f / SP3) - m * m;
        float a = G[t] * rsqrtf(var + EPSF);
        AB[t] = a; AB[64 + t] = BE[t] - m * a;
    }
}

// ---- head MFMA: 4 waves (co-half x col-half), BN2+ReLU fused on B-load ----
__global__ __launch_bounds__(256) void k_headm(const unsigned short* __restrict__ X,
                                               const unsigned short* __restrict__ AH,
                                               const float* __restrict__ AB2,
                                               const float* __restrict__ BH,
                                               float* __restrict__ O, int dup2) {
    __shared__ float sab[128];
    int t = threadIdx.x;
    if (t < 128) sab[t] = AB2[t];
    __syncthreads();
    int wv = t >> 6, l = t & 63, khalf = l >> 5;
    int coh = wv >> 1, colh = wv & 1;
    int sp = blockIdx.x * 64 + colh * 32 + (l & 31);
    f32x16 acc[4] = {};
#pragma unroll
    for (int cib = 0; cib < 16; ++cib) {
        int d = cib >> 2, ch0 = (cib & 3) * 16 + khalf * 8;
        uint4 raw = *(const uint4*)(X + ((size_t)(d * SP2 + sp)) * 64 + ch0);
        unsigned r[4] = {raw.x, raw.y, raw.z, raw.w}, qq[4];
#pragma unroll
        for (int k2 = 0; k2 < 4; ++k2) {
            int c0 = ch0 + k2 * 2;
            float lo = bf2f((unsigned short)(r[k2] & 0xffff));
            float hi = bf2f((unsigned short)(r[k2] >> 16));
            lo = fmaxf(fmaf(sab[c0], lo, sab[64 + c0]), 0.f);
            hi = fmaxf(fmaf(sab[c0 + 1], hi, sab[64 + c0 + 1]), 0.f);
            qq[k2] = (unsigned)f2bf(lo) | ((unsigned)f2bf(hi) << 16);
        }
        short8 bfr = __builtin_bit_cast(short8, make_uint4(qq[0], qq[1], qq[2], qq[3]));
#pragma unroll
        for (int mi = 0; mi < 4; ++mi) {
            const uint4* ap = (const uint4*)AH + (cib * 8 + coh * 4 + mi) * 64 + l;
            short8 afr = __builtin_bit_cast(short8, *ap);
            acc[mi] = __builtin_amdgcn_mfma_f32_32x32x16_bf16(afr, bfr, acc[mi], 0, 0, 0);
        }
    }
#pragma unroll
    for (int mi = 0; mi < 4; ++mi) {
#pragma unroll
        for (int rq = 0; rq < 4; ++rq) {
            int co0 = coh * 128 + mi * 32 + rq * 8 + khalf * 4;
            float4 bb = *(const float4*)(BH + co0);
#pragma unroll
            for (int j = 0; j < 4; ++j) {
                float val = acc[mi][rq * 4 + j] + ((const float*)&bb)[j];
                size_t o = (size_t)(co0 + j) * SP2 + sp;
                O[o] = val;
                if (dup2) O[10240000 + o] = val;
            }
        }
    }
}

// ---- duplicate batch0 -> batch1 (fallback mode only) ----
__global__ __launch_bounds__(256) void k_dup(float* __restrict__ O) {
    int i = blockIdx.x * 256 + threadIdx.x;
    float4* p = reinterpret_cast<float4*>(O);
    p[OUTC * SP2 / 4 + i] = p[i];
}

extern "C" void kernel_launch(void* const* d_in, const int* in_sizes, int n_in,
                              void* d_out, int out_size, void* d_ws, size_t ws_size,
                              hipStream_t stream) {
    const float* vox = (const float*)d_in[0];
    const int*   idx = (const int*)d_in[1];
    const float* w1  = (const float*)d_in[3];
    const float* b1  = (const float*)d_in[4];
    const float* g1  = (const float*)d_in[5];
    const float* be1 = (const float*)d_in[6];
    const float* w2  = (const float*)d_in[7];
    const float* b2  = (const float*)d_in[8];
    const float* g2  = (const float*)d_in[9];
    const float* be2 = (const float*)d_in[10];
    const float* wh  = (const float*)d_in[11];
    const float* bh  = (const float*)d_in[12];

    float* out = (float*)d_out;
    char* ws = (char*)d_ws;
    unsigned short* grid8  = (unsigned short*)ws;                 // 2,560,000 B
    float*          ab1    = (float*)(ws + 2560000);              // 512 B
    float*          ab2    = (float*)(ws + 2560512);              // 512 B
    float*          part   = (float*)(ws + 2561024);              // 131,072 B (256*128*4)
    unsigned short* apack1 = (unsigned short*)(ws + 2692096);     // 28,672 B
    unsigned short* apack2 = (unsigned short*)(ws + 2720768);     // 221,184 B
    unsigned short* apackh = (unsigned short*)(ws + 2941952);     // 131,072 B

    bool ws_mode = ws_size >= 44033024u;
    unsigned short* y1b, * y2b;
    if (ws_mode) {
        y1b = (unsigned short*)(ws + 3073024);
        y2b = (unsigned short*)(ws + 23553024);
    } else {
        y1b = (unsigned short*)(out + 10240000);
        y2b = y1b + 10240000;
    }

    k_zero<<<625, 256, 0, stream>>>((uint4*)grid8);   // 625*256*16 B = 2.56 MB
    k_prep<<<901, 256, 0, stream>>>(vox, idx, w1, w2, wh, grid8, apack1, apack2, apackh);
    k_conv1m<<<1250, 128, 0, stream>>>(grid8, apack1, b1, y1b);
    k_stats2p<<<256, 256, 0, stream>>>(y1b, part);
    k_statsf<<<1, 1024, 0, stream>>>(part, g1, be1, ab1);
    k_conv2m<<<1250, 256, 0, stream>>>(y1b, apack2, ab1, b2, y2b);
    k_stats2p<<<256, 256, 0, stream>>>(y2b, part);
    k_statsf<<<1, 1024, 0, stream>>>(part, g2, be2, ab2);
    k_headm<<<625, 256, 0, stream>>>(y2b, apackh, ab2, bh, out, ws_mode ? 1 : 0);
    if (!ws_mode)
        k_dup<<<10000, 256, 0, stream>>>(out);
}